// Round 17
// baseline (1982.018 us; speedup 1.0000x reference)
//
#include <hip/hip_runtime.h>
#include <math.h>

// Problem dims
#define B_    512
#define T_    125
#define N_    66
#define D_    20
#define H_    256
#define ST_   6
#define THIS_ 25
#define C_    (N_*H_)     // 16896 channels for BN
#define NBGS  64          // batch groups for BN stats
#define BPGS  (B_/NBGS)   // 8
#define EPS_  1e-5f

#define ASTR  264         // As row stride (ushorts)
#define MSTR  104         // XLT/oT row stride (ushorts), 96 used
#define ESTR  40          // genc As row stride (32 used)

typedef __attribute__((ext_vector_type(8))) short bf16x8;
typedef __attribute__((ext_vector_type(4))) float f32x4;

__device__ __forceinline__ ushort f2bf(float f) {
    unsigned u = __float_as_uint(f);
    u += 0x7fffu + ((u >> 16) & 1u);       // round-to-nearest-even
    return (ushort)(u >> 16);
}
__device__ __forceinline__ float bf2f(ushort h) {
    return __uint_as_float((unsigned)h << 16);
}

// tanh(x) = 1 - 2/(e^{2x}+1); v_exp/v_rcp ~1ulp, exact at +-inf.
__device__ __forceinline__ float fast_tanh(float x) {
    float t, r;
    const float z = x * 2.885390081777927f;   // 2*log2(e)
    asm("v_exp_f32 %0, %1" : "=v"(t) : "v"(z));
    const float tp1 = t + 1.f;
    asm("v_rcp_f32 %0, %1" : "=v"(r) : "v"(tp1));
    return 1.f - 2.f * r;
}

// Fused staging element: t = tanh(y*sc+sh) (+ hin bf16); optional hout (bf16).
__device__ __forceinline__ bf16x8 stage8(const ushort* __restrict__ Yin,
                                         const float* __restrict__ SC,
                                         const float* __restrict__ SH,
                                         const ushort* __restrict__ hin,
                                         ushort* __restrict__ hout,
                                         int ch, size_t g) {
    const bf16x8 raw = *(const bf16x8*)(Yin + g);
    float sv[8], hv[8], t[8];
    *(float4*)&sv[0] = *(const float4*)(SC + ch);
    *(float4*)&sv[4] = *(const float4*)(SC + ch + 4);
    *(float4*)&hv[0] = *(const float4*)(SH + ch);
    *(float4*)&hv[4] = *(const float4*)(SH + ch + 4);
    #pragma unroll
    for (int j = 0; j < 8; ++j)
        t[j] = fast_tanh(fmaf(bf2f((ushort)raw[j]), sv[j], hv[j]));
    if (hin) {
        const bf16x8 rv = *(const bf16x8*)(hin + g);
        #pragma unroll
        for (int j = 0; j < 8; ++j) t[j] += bf2f((ushort)rv[j]);
    }
    bf16x8 v;
    #pragma unroll
    for (int j = 0; j < 8; ++j) v[j] = (short)f2bf(t[j]);
    if (hout) *(bf16x8*)(hout + g) = v;
    return v;
}

// ---------------------------------------------------------------------------
// Weight transpose+convert: WT[s][f][k] = bf16(W[s][k][f]).  grid (4,4,ST).
// ---------------------------------------------------------------------------
__global__ __launch_bounds__(256) void k_wtrans(const float* __restrict__ W,
                                                ushort* __restrict__ WT) {
    __shared__ ushort t[64][65];
    const int s = blockIdx.z;
    const int kb = blockIdx.x * 64, fb = blockIdx.y * 64;
    const int tid = threadIdx.x;
    const int c = tid & 63;
    const int r4 = tid >> 6;
    for (int rr = 0; rr < 64; rr += 4) {
        const int r = rr + r4;
        t[r][c] = f2bf(W[(size_t)s * 65536 + (size_t)(kb + r) * 256 + fb + c]);
    }
    __syncthreads();
    for (int rr = 0; rr < 64; rr += 4) {
        const int f = rr + r4;
        WT[(size_t)s * 65536 + (size_t)(fb + f) * 256 + kb + c] = t[c][f];
    }
}

// ---------------------------------------------------------------------------
// att pad+convert: P[s][r][m] = bf16(A[s][r][m]) for r,m<66 else 0.  [80][96]
// ---------------------------------------------------------------------------
__global__ __launch_bounds__(256) void k_aprep(const float* __restrict__ A,
                                               ushort* __restrict__ P,
                                               int S) {
    const int idx = blockIdx.x * 256 + threadIdx.x;
    if (idx >= S * 80 * 96) return;
    const int s = idx / 7680, rm = idx % 7680;
    const int r = rm / 96, m = rm % 96;
    const float v = (r < N_ && m < N_) ? A[(size_t)s * N_ * N_ + r * N_ + m] : 0.f;
    P[idx] = f2bf(v);
}

// ---------------------------------------------------------------------------
// decw pad+transpose: dwT[f][k] = bf16(decw[k][f]) for f<20 else 0.  [32][256]
// ---------------------------------------------------------------------------
__global__ __launch_bounds__(256) void k_dwprep(const float* __restrict__ dw,
                                                ushort* __restrict__ dwT) {
    const int idx = blockIdx.x * 256 + threadIdx.x;
    if (idx >= 32 * 256) return;
    const int f = idx / 256, k = idx % 256;
    const float v = (f < D_) ? dw[(size_t)k * D_ + f] : 0.f;
    dwT[idx] = f2bf(v);
}

// ---------------------------------------------------------------------------
// encw pad+transpose: ewT[f][k] = bf16(encw[k][f]) for k<20 else 0.  [256][32]
// ---------------------------------------------------------------------------
__global__ __launch_bounds__(256) void k_ewprep(const float* __restrict__ ew,
                                                ushort* __restrict__ ewT) {
    const int idx = blockIdx.x * 256 + threadIdx.x;
    if (idx >= 256 * 32) return;
    const int f = idx / 32, k = idx % 32;
    const float v = (k < D_) ? ew[(size_t)k * H_ + f] : 0.f;
    ewT[idx] = f2bf(v);
}

// ---------------------------------------------------------------------------
// DCT along time: xd[b][n][d] = sum_t trans[d][t] * x[b][t][n]
// ---------------------------------------------------------------------------
__global__ __launch_bounds__(256) void k_dct(const float* __restrict__ x,
                                             const float* __restrict__ tm,
                                             float* __restrict__ xd) {
    __shared__ float xs[T_*N_];
    __shared__ float tl[D_*T_];
    const int b = blockIdx.x, tid = threadIdx.x;
    const float* xb = x + (size_t)b * T_ * N_;
    for (int i = tid; i < T_*N_; i += 256) xs[i] = xb[i];
    for (int i = tid; i < D_*T_; i += 256) tl[i] = tm[i];
    __syncthreads();
    for (int p = tid; p < N_*D_; p += 256) {
        const int n = p / D_, d = p % D_;
        float acc = 0.f;
        for (int t = 0; t < T_; ++t)
            acc = fmaf(tl[d*T_ + t], xs[t*N_ + n], acc);
        xd[(size_t)b * N_ * D_ + p] = acc;
    }
}

// ---------------------------------------------------------------------------
// Encoder GC, dual-MFMA: per-batch block. (unchanged r14)
// ---------------------------------------------------------------------------
__global__ __launch_bounds__(256) void k_genc2(const float* __restrict__ xd,
                                               const ushort* __restrict__ ewT,
                                               const ushort* __restrict__ attP,
                                               const float* __restrict__ bias,
                                               ushort* __restrict__ Ybf) {
    __shared__ __align__(16) ushort As[80 * ESTR];
    __shared__ __align__(16) ushort XLT[256 * MSTR];
    const int b    = blockIdx.x;
    const int tid  = threadIdx.x;
    const int lane = tid & 63;
    const int wc   = tid >> 6;
    const int kq   = lane >> 4;
    const int fr   = lane & 15;

    const int ar1 = tid >> 2;
    const int ak  = (tid & 3) * 8;
    const int ar2 = 64 + (tid >> 2);
    {
        bf16x8 v;
        #pragma unroll
        for (int j = 0; j < 8; ++j) {
            const int k = ak + j;
            v[j] = (k < D_) ? (short)f2bf(xd[((size_t)b * N_ + ar1) * D_ + k]) : (short)0;
        }
        *(bf16x8*)&As[ar1 * ESTR + ak] = v;
    }
    if (tid < 64) {
        bf16x8 v;
        #pragma unroll
        for (int j = 0; j < 8; ++j) {
            const int k = ak + j;
            v[j] = (ar2 < N_ && k < D_) ?
                   (short)f2bf(xd[((size_t)b * N_ + ar2) * D_ + k]) : (short)0;
        }
        *(bf16x8*)&As[ar2 * ESTR + ak] = v;
    }
    __syncthreads();

    f32x4 acc[5][4] = {};
    {
        bf16x8 a[5], bv[4];
        #pragma unroll
        for (int m = 0; m < 5; ++m)
            a[m] = *(const bf16x8*)&As[(m * 16 + fr) * ESTR + kq * 8];
        #pragma unroll
        for (int n = 0; n < 4; ++n)
            bv[n] = *(const bf16x8*)(ewT + (size_t)(wc * 64 + n * 16 + fr) * 32 + kq * 8);
        #pragma unroll
        for (int m = 0; m < 5; ++m)
            #pragma unroll
            for (int n = 0; n < 4; ++n)
                acc[m][n] = __builtin_amdgcn_mfma_f32_16x16x32_bf16(
                                a[m], bv[n], acc[m][n], 0, 0, 0);
    }
    __syncthreads();

    {
        bf16x8 z = {};
        *(bf16x8*)&XLT[(wc * 64 + lane) * MSTR + 80] = z;
        *(bf16x8*)&XLT[(wc * 64 + lane) * MSTR + 88] = z;
    }
    #pragma unroll
    for (int m = 0; m < 5; ++m)
        #pragma unroll
        for (int n = 0; n < 4; ++n)
            #pragma unroll
            for (int j = 0; j < 4; ++j)
                XLT[(wc * 64 + n * 16 + fr) * MSTR + m * 16 + kq * 4 + j] =
                    f2bf(acc[m][n][j]);

    f32x4 acc2[5][4] = {};
    for (int kt = 0; kt < 3; ++kt) {
        const int kb = kt * 32;
        bf16x8 a2[5], b2[4];
        #pragma unroll
        for (int m = 0; m < 5; ++m)
            a2[m] = *(const bf16x8*)(attP + (size_t)(m * 16 + fr) * 96 + kb + kq * 8);
        #pragma unroll
        for (int n = 0; n < 4; ++n)
            b2[n] = *(const bf16x8*)&XLT[(wc * 64 + n * 16 + fr) * MSTR + kb + kq * 8];
        #pragma unroll
        for (int m = 0; m < 5; ++m)
            #pragma unroll
            for (int n = 0; n < 4; ++n)
                acc2[m][n] = __builtin_amdgcn_mfma_f32_16x16x32_bf16(
                                a2[m], b2[n], acc2[m][n], 0, 0, 0);
    }
    float bsv[4];
    #pragma unroll
    for (int n = 0; n < 4; ++n) bsv[n] = bias[wc * 64 + n * 16 + fr];
    #pragma unroll
    for (int m = 0; m < 5; ++m)
        #pragma unroll
        for (int n = 0; n < 4; ++n)
            #pragma unroll
            for (int j = 0; j < 4; ++j) {
                const int row = m * 16 + kq * 4 + j;
                if (row < N_) {
                    const int f = wc * 64 + n * 16 + fr;
                    Ybf[(size_t)b * C_ + row * H_ + f] = f2bf(acc2[m][n][j] + bsv[n]);
                }
            }
}

// ---------------------------------------------------------------------------
// Stage GC, dual-MFMA with fused BN+tanh(+residual update, bf16 h) staging.
// (unchanged r14)
// ---------------------------------------------------------------------------
__global__ __launch_bounds__(256) void k_gc(const ushort* __restrict__ Yin,
                                            const float* __restrict__ SC,
                                            const float* __restrict__ SH,
                                            const ushort* __restrict__ hin,
                                            ushort* __restrict__ hout,
                                            const ushort* __restrict__ WT,
                                            const ushort* __restrict__ attP,
                                            const float* __restrict__ bias,
                                            ushort* __restrict__ Ybf) {
    __shared__ __align__(16) ushort smem[256 * MSTR];   // 53,248 B (union)
    ushort* As  = smem;
    ushort* XLT = smem;
    const int b    = blockIdx.x;
    const int tid  = threadIdx.x;
    const int lane = tid & 63;
    const int wc   = tid >> 6;
    const int kq   = lane >> 4;
    const int fr   = lane & 15;

    const int ar1 = tid >> 2;
    const int ak  = (tid & 3) * 8;
    const int ar2 = 64 + (tid >> 2);

    for (int kt = 0; kt < 8; ++kt) {
        const int kk = kt * 32 + ak;
        *(bf16x8*)&As[ar1 * ASTR + kk] =
            stage8(Yin, SC, SH, hin, hout, ar1 * H_ + kk,
                   ((size_t)b * N_ + ar1) * H_ + kk);
    }
    if (tid < 64) {
        for (int kt = 0; kt < 8; ++kt) {
            const int kk = kt * 32 + ak;
            bf16x8 v = {};
            if (ar2 < N_)
                v = stage8(Yin, SC, SH, hin, hout, ar2 * H_ + kk,
                           ((size_t)b * N_ + ar2) * H_ + kk);
            *(bf16x8*)&As[ar2 * ASTR + kk] = v;
        }
    }
    __syncthreads();

    f32x4 acc[5][4] = {};
    for (int kt = 0; kt < 8; ++kt) {
        const int kb = kt * 32;
        bf16x8 a[5], bv[4];
        #pragma unroll
        for (int m = 0; m < 5; ++m)
            a[m] = *(const bf16x8*)&As[(m * 16 + fr) * ASTR + kb + kq * 8];
        #pragma unroll
        for (int n = 0; n < 4; ++n)
            bv[n] = *(const bf16x8*)(WT + (size_t)(wc * 64 + n * 16 + fr) * H_ + kb + kq * 8);
        #pragma unroll
        for (int m = 0; m < 5; ++m)
            #pragma unroll
            for (int n = 0; n < 4; ++n)
                acc[m][n] = __builtin_amdgcn_mfma_f32_16x16x32_bf16(
                                a[m], bv[n], acc[m][n], 0, 0, 0);
    }
    __syncthreads();   // As dead -> reuse as XLT

    {
        bf16x8 z = {};
        *(bf16x8*)&XLT[(wc * 64 + lane) * MSTR + 80] = z;
        *(bf16x8*)&XLT[(wc * 64 + lane) * MSTR + 88] = z;
    }
    #pragma unroll
    for (int m = 0; m < 5; ++m)
        #pragma unroll
        for (int n = 0; n < 4; ++n)
            #pragma unroll
            for (int j = 0; j < 4; ++j)
                XLT[(wc * 64 + n * 16 + fr) * MSTR + m * 16 + kq * 4 + j] =
                    f2bf(acc[m][n][j]);
    // no barrier: each wave reads only its own strip

    f32x4 acc2[5][4] = {};
    for (int kt = 0; kt < 3; ++kt) {
        const int kb = kt * 32;
        bf16x8 a2[5], b2[4];
        #pragma unroll
        for (int m = 0; m < 5; ++m)
            a2[m] = *(const bf16x8*)(attP + (size_t)(m * 16 + fr) * 96 + kb + kq * 8);
        #pragma unroll
        for (int n = 0; n < 4; ++n)
            b2[n] = *(const bf16x8*)&XLT[(wc * 64 + n * 16 + fr) * MSTR + kb + kq * 8];
        #pragma unroll
        for (int m = 0; m < 5; ++m)
            #pragma unroll
            for (int n = 0; n < 4; ++n)
                acc2[m][n] = __builtin_amdgcn_mfma_f32_16x16x32_bf16(
                                a2[m], b2[n], acc2[m][n], 0, 0, 0);
    }
    float bsv[4];
    #pragma unroll
    for (int n = 0; n < 4; ++n) bsv[n] = bias[wc * 64 + n * 16 + fr];
    #pragma unroll
    for (int m = 0; m < 5; ++m)
        #pragma unroll
        for (int n = 0; n < 4; ++n)
            #pragma unroll
            for (int j = 0; j < 4; ++j) {
                const int row = m * 16 + kq * 4 + j;
                if (row < N_) {
                    const int f = wc * 64 + n * 16 + fr;
                    Ybf[(size_t)b * C_ + row * H_ + f] = f2bf(acc2[m][n][j] + bsv[n]);
                }
            }
}

// ---------------------------------------------------------------------------
// Fused BN stats + finalize: grid (17, 64).  All blocks write their partial
// (identical order to r14 k_stats), then release via device-scope atomic.
// The 17 blockIdx.y==0 blocks spin until all 1088 partials land, then do the
// r14 k_bnfin reduce (fixed order -> bitwise deterministic).
// Deadlock-safe: zero-LDS, 4 waves/block -> all 1088 blocks co-resident.
// ---------------------------------------------------------------------------
__global__ __launch_bounds__(256) void k_statsfin(const ushort* __restrict__ v,
                                                  float* __restrict__ P1,
                                                  float* __restrict__ P2,
                                                  const float* __restrict__ gam,
                                                  const float* __restrict__ bet,
                                                  float* __restrict__ SC,
                                                  float* __restrict__ SH,
                                                  unsigned* __restrict__ ctr) {
    const int tid = threadIdx.x;
    const int c4  = blockIdx.x * 256 + tid;
    const bool act = (c4 < C_ / 4);
    const int g = blockIdx.y;

    if (act) {
        float4 s1 = make_float4(0.f,0.f,0.f,0.f), s2 = make_float4(0.f,0.f,0.f,0.f);
        const ushort4* vp = (const ushort4*)v;
        for (int i = 0; i < BPGS; ++i) {
            const int b = g * BPGS + i;
            const ushort4 t4 = vp[(size_t)b * (C_ / 4) + c4];
            const float tx = bf2f(t4.x), ty = bf2f(t4.y),
                        tz = bf2f(t4.z), tw = bf2f(t4.w);
            s1.x += tx; s1.y += ty; s1.z += tz; s1.w += tw;
            s2.x = fmaf(tx, tx, s2.x); s2.y = fmaf(ty, ty, s2.y);
            s2.z = fmaf(tz, tz, s2.z); s2.w = fmaf(tw, tw, s2.w);
        }
        ((float4*)(P1 + (size_t)g * C_))[c4] = s1;
        ((float4*)(P2 + (size_t)g * C_))[c4] = s2;
    }
    __threadfence();          // release partials (device scope)
    __syncthreads();
    if (tid == 0) atomicAdd(ctr, 1u);

    if (blockIdx.y != 0) return;

    if (tid == 0) {
        while (atomicAdd(ctr, 0u) < 17u * 64u)
            __builtin_amdgcn_s_sleep(2);
    }
    __syncthreads();
    __threadfence();          // acquire all partials

    if (act) {
        float4 s1 = make_float4(0.f,0.f,0.f,0.f), s2 = make_float4(0.f,0.f,0.f,0.f);
        for (int gg = 0; gg < NBGS; ++gg) {
            const float4 a = ((const float4*)(P1 + (size_t)gg * C_))[c4];
            const float4 b = ((const float4*)(P2 + (size_t)gg * C_))[c4];
            s1.x += a.x; s1.y += a.y; s1.z += a.z; s1.w += a.w;
            s2.x += b.x; s2.y += b.y; s2.z += b.z; s2.w += b.w;
        }
        const float inv = 1.f / (float)B_;
        const float4 gm = ((const float4*)gam)[c4];
        const float4 bt = ((const float4*)bet)[c4];
        float4 sc, sh;
        float mu, var;
        mu = s1.x*inv; var = fmaf(-mu, mu, s2.x*inv); sc.x = gm.x*rsqrtf(var+EPS_); sh.x = bt.x - mu*sc.x;
        mu = s1.y*inv; var = fmaf(-mu, mu, s2.y*inv); sc.y = gm.y*rsqrtf(var+EPS_); sh.y = bt.y - mu*sc.y;
        mu = s1.z*inv; var = fmaf(-mu, mu, s2.z*inv); sc.z = gm.z*rsqrtf(var+EPS_); sh.z = bt.z - mu*sc.z;
        mu = s1.w*inv; var = fmaf(-mu, mu, s2.w*inv); sc.w = gm.w*rsqrtf(var+EPS_); sh.w = bt.w - mu*sc.w;
        ((float4*)SC)[c4] = sc;
        ((float4*)SH)[c4] = sh;
    }
}

// ---------------------------------------------------------------------------
// Fully fused decoder with fused final h-update (bf16 h).  (unchanged r14)
// ---------------------------------------------------------------------------
__global__ __launch_bounds__(256) void k_dec2(const ushort* __restrict__ Yin,
                                              const float* __restrict__ SC,
                                              const float* __restrict__ SH,
                                              const ushort* __restrict__ hin,
                                              const ushort* __restrict__ dwT,
                                              const ushort* __restrict__ aPd,
                                              const float* __restrict__ db,
                                              const float* __restrict__ xd,
                                              const float* __restrict__ itm,
                                              const float* __restrict__ x,
                                              float* __restrict__ out) {
    __shared__ __align__(16) ushort As[80 * ASTR];
    __shared__ __align__(16) ushort oT[32 * MSTR];
    __shared__ float odL[N_ * 21];
    __shared__ float itL[T_ * D_];
    const int b    = blockIdx.x;
    const int tid  = threadIdx.x;
    const int lane = tid & 63;
    const int wc   = tid >> 6;
    const int kq   = lane >> 4;
    const int fr   = lane & 15;

    for (int i = tid; i < T_*D_; i += 256) {
        const int t = i / D_, d = i % D_;
        itL[i] = itm[t * T_ + d];
    }
    const int ar1 = tid >> 2;
    const int ak  = (tid & 3) * 8;
    const int ar2 = 64 + (tid >> 2);
    for (int kt = 0; kt < 8; ++kt) {
        const int kk = kt * 32 + ak;
        *(bf16x8*)&As[ar1 * ASTR + kk] =
            stage8(Yin, SC, SH, hin, nullptr, ar1 * H_ + kk,
                   ((size_t)b * N_ + ar1) * H_ + kk);
    }
    if (tid < 64) {
        for (int kt = 0; kt < 8; ++kt) {
            const int kk = kt * 32 + ak;
            bf16x8 v = {};
            if (ar2 < N_)
                v = stage8(Yin, SC, SH, hin, nullptr, ar2 * H_ + kk,
                           ((size_t)b * N_ + ar2) * H_ + kk);
            *(bf16x8*)&As[ar2 * ASTR + kk] = v;
        }
    }
    if (tid >= 128 && tid < 160) {
        bf16x8 z = {};
        *(bf16x8*)&oT[(tid - 128) * MSTR + 80] = z;
        *(bf16x8*)&oT[(tid - 128) * MSTR + 88] = z;
    }
    __syncthreads();

    if (wc < 2) {
        f32x4 acc[5] = {};
        for (int kt = 0; kt < 8; ++kt) {
            const int kb = kt * 32;
            bf16x8 a[5];
            #pragma unroll
            for (int m = 0; m < 5; ++m)
                a[m] = *(const bf16x8*)&As[(m * 16 + fr) * ASTR + kb + kq * 8];
            const bf16x8 bv = *(const bf16x8*)(dwT + (size_t)(wc * 16 + fr) * H_ + kb + kq * 8);
            #pragma unroll
            for (int m = 0; m < 5; ++m)
                acc[m] = __builtin_amdgcn_mfma_f32_16x16x32_bf16(a[m], bv, acc[m], 0, 0, 0);
        }
        #pragma unroll
        for (int m = 0; m < 5; ++m)
            #pragma unroll
            for (int j = 0; j < 4; ++j)
                oT[(wc * 16 + fr) * MSTR + m * 16 + kq * 4 + j] = f2bf(acc[m][j]);
    }
    __syncthreads();

    if (wc < 2) {
        f32x4 acc2[5] = {};
        for (int kt = 0; kt < 3; ++kt) {
            const int kb = kt * 32;
            bf16x8 a2[5];
            #pragma unroll
            for (int m = 0; m < 5; ++m)
                a2[m] = *(const bf16x8*)(aPd + (size_t)(m * 16 + fr) * 96 + kb + kq * 8);
            const bf16x8 b2 = *(const bf16x8*)&oT[(wc * 16 + fr) * MSTR + kb + kq * 8];
            #pragma unroll
            for (int m = 0; m < 5; ++m)
                acc2[m] = __builtin_amdgcn_mfma_f32_16x16x32_bf16(a2[m], b2, acc2[m], 0, 0, 0);
        }
        const int d = wc * 16 + fr;
        if (d < D_) {
            const float dbv = db[d];
            #pragma unroll
            for (int m = 0; m < 5; ++m)
                #pragma unroll
                for (int j = 0; j < 4; ++j) {
                    const int n = m * 16 + kq * 4 + j;
                    if (n < N_)
                        odL[n * 21 + d] = acc2[m][j] + dbv
                                        + xd[(size_t)b * N_ * D_ + n * D_ + d];
                }
        }
    }
    __syncthreads();

    const float* xb = x + (size_t)b * T_ * N_;
    float* ob = out + (size_t)b * T_ * N_;
    for (int q = tid; q < T_*N_; q += 256) {
        const int t = q / N_, n = q % N_;
        float o;
        if (t < THIS_) {
            o = xb[q];
        } else {
            o = 0.f;
            #pragma unroll 4
            for (int d = 0; d < D_; ++d)
                o = fmaf(itL[t * D_ + d], odL[n * 21 + d], o);
        }
        ob[q] = o;
    }
}

// ---------------------------------------------------------------------------
extern "C" void kernel_launch(void* const* d_in, const int* in_sizes, int n_in,
                              void* d_out, int out_size, void* d_ws, size_t ws_size,
                              hipStream_t stream) {
    const float* x    = (const float*)d_in[0];
    const float* tm   = (const float*)d_in[1];
    const float* itm  = (const float*)d_in[2];
    const float* encw = (const float*)d_in[3];
    const float* enca = (const float*)d_in[4];
    const float* encb = (const float*)d_in[5];
    const float* bn0g = (const float*)d_in[6];
    const float* bn0b = (const float*)d_in[7];
    const float* g1w  = (const float*)d_in[8];
    const float* g1a  = (const float*)d_in[9];
    const float* g1b  = (const float*)d_in[10];
    const float* b1g  = (const float*)d_in[11];
    const float* b1b  = (const float*)d_in[12];
    const float* g2w  = (const float*)d_in[13];
    const float* g2a  = (const float*)d_in[14];
    const float* g2b  = (const float*)d_in[15];
    const float* b2g  = (const float*)d_in[16];
    const float* b2b  = (const float*)d_in[17];
    const float* decw = (const float*)d_in[18];
    const float* deca = (const float*)d_in[19];
    const float* decb = (const float*)d_in[20];
    float* out = (float*)d_out;

    // ws layout (round-1 footprint, proven)
    float* ws = (float*)d_ws;
    float* xd = ws;                         //   675840 floats
    float* hslot = xd + 675840;             //  8650752 floats
    float* slotA = hslot + 8650752;         //  8650752
    float* slotB = slotA + 8650752;         //  8650752
    float* oldP1 = slotB + 8650752;         //   270336 (unused)
    float* oldP2 = oldP1 + 270336;          //   270336 (unused)
    float* SC = oldP2 + 270336;             //    16896
    float* SH = SC + 16896;                 //    16896
    ushort* hbf = (ushort*)hslot;           //  4325376 u16
    ushort* WT1 = (ushort*)slotA;           //   393216 u16
    ushort* WT2 = WT1 + 393216;             //   393216 u16
    ushort* ybf = WT2 + 393216;             //  8650752 u16
    ushort* aP1 = ybf + 8650752;            //    46080 u16
    ushort* aP2 = aP1 + 46080;              //    46080 u16
    ushort* aPd = aP2 + 46080;              //     7680 u16
    ushort* aPe = aPd + 7680;               //     7680 u16
    ushort* dwT = aPe + 7680;               //     8192 u16
    ushort* ewT = dwT + 8192;               //     8192 u16
    unsigned* ctrs = (unsigned*)(ewT + 8192); //    16 u32 (13 used)
    float* P1 = slotB;                      //  1081344 f (64 groups)
    float* P2 = P1 + (size_t)NBGS * C_;     //  1081344 f

    const dim3 blk(256);
    const dim3 gSF(17, NBGS);

    // zero the barrier counters (graph-capture legal)
    hipMemsetAsync(ctrs, 0, 16 * sizeof(unsigned), stream);

    // preprocessing
    k_wtrans<<<dim3(4,4,ST_), blk, 0, stream>>>(g1w, WT1);
    k_wtrans<<<dim3(4,4,ST_), blk, 0, stream>>>(g2w, WT2);
    k_aprep<<<180, blk, 0, stream>>>(g1a, aP1, ST_);
    k_aprep<<<180, blk, 0, stream>>>(g2a, aP2, ST_);
    k_aprep<<<30, blk, 0, stream>>>(deca, aPd, 1);
    k_aprep<<<30, blk, 0, stream>>>(enca, aPe, 1);
    k_dwprep<<<32, blk, 0, stream>>>(decw, dwT);
    k_ewprep<<<32, blk, 0, stream>>>(encw, ewT);

    k_dct<<<B_, blk, 0, stream>>>(x, tm, xd);

    // encoder (dual-MFMA) -> ybf; bn0 stats+coefs (fused)
    int ci = 0;
    k_genc2<<<B_, blk, 0, stream>>>(xd, ewT, aPe, encb, ybf);
    k_statsfin<<<gSF, blk, 0, stream>>>(ybf, P1, P2, bn0g, bn0b, SC, SH,
                                        ctrs + ci++);

    for (int s = 0; s < ST_; ++s) {
        // gc1: A = tanh(bn(y)) (+h for s>0); h updated; ybf = att1*(A@w1)+b1
        k_gc<<<B_, blk, 0, stream>>>(ybf, SC, SH, s ? hbf : nullptr, hbf,
                                     WT1 + s*H_*H_, aP1 + s*7680,
                                     g1b + s*H_, ybf);
        k_statsfin<<<gSF, blk, 0, stream>>>(ybf, P1, P2, b1g + s*C_,
                                            b1b + s*C_, SC, SH, ctrs + ci++);
        // gc2: A = tanh(bn1(y)); ybf = att2*(A@w2)+b2
        k_gc<<<B_, blk, 0, stream>>>(ybf, SC, SH, nullptr, nullptr,
                                     WT2 + s*H_*H_, aP2 + s*7680,
                                     g2b + s*H_, ybf);
        k_statsfin<<<gSF, blk, 0, stream>>>(ybf, P1, P2, b2g + s*C_,
                                            b2b + s*C_, SC, SH, ctrs + ci++);
    }

    // decoder with fused final h-update (h6 = tanh(bn2(y2_5)) + h5)
    k_dec2<<<B_, blk, 0, stream>>>(ybf, SC, SH, hbf, dwT, aPd, decb, xd, itm,
                                   x, out);
}

// Round 18
// 596.380 us; speedup vs baseline: 3.3234x; 3.3234x over previous
//
#include <hip/hip_runtime.h>
#include <math.h>

// Problem dims
#define B_    512
#define T_    125
#define N_    66
#define D_    20
#define H_    256
#define ST_   6
#define THIS_ 25
#define C_    (N_*H_)     // 16896 channels for BN
#define NBGS  64          // batch groups for BN stats
#define BPGS  (B_/NBGS)   // 8
#define EPS_  1e-5f

#define ASTR  264         // As row stride (ushorts)
#define MSTR  104         // XLT/oT row stride (ushorts), 96 used
#define ESTR  40          // genc As row stride (32 used)

typedef __attribute__((ext_vector_type(8))) short bf16x8;
typedef __attribute__((ext_vector_type(4))) float f32x4;

__device__ __forceinline__ ushort f2bf(float f) {
    unsigned u = __float_as_uint(f);
    u += 0x7fffu + ((u >> 16) & 1u);       // round-to-nearest-even
    return (ushort)(u >> 16);
}
__device__ __forceinline__ float bf2f(ushort h) {
    return __uint_as_float((unsigned)h << 16);
}

// tanh(x) = 1 - 2/(e^{2x}+1); v_exp/v_rcp ~1ulp, exact at +-inf.
__device__ __forceinline__ float fast_tanh(float x) {
    float t, r;
    const float z = x * 2.885390081777927f;   // 2*log2(e)
    asm("v_exp_f32 %0, %1" : "=v"(t) : "v"(z));
    const float tp1 = t + 1.f;
    asm("v_rcp_f32 %0, %1" : "=v"(r) : "v"(tp1));
    return 1.f - 2.f * r;
}

// Fused staging element: t = tanh(y*sc+sh) (+ hin bf16); optional hout (bf16).
__device__ __forceinline__ bf16x8 stage8(const ushort* __restrict__ Yin,
                                         const float* __restrict__ SC,
                                         const float* __restrict__ SH,
                                         const ushort* __restrict__ hin,
                                         ushort* __restrict__ hout,
                                         int ch, size_t g) {
    const bf16x8 raw = *(const bf16x8*)(Yin + g);
    float sv[8], hv[8], t[8];
    *(float4*)&sv[0] = *(const float4*)(SC + ch);
    *(float4*)&sv[4] = *(const float4*)(SC + ch + 4);
    *(float4*)&hv[0] = *(const float4*)(SH + ch);
    *(float4*)&hv[4] = *(const float4*)(SH + ch + 4);
    #pragma unroll
    for (int j = 0; j < 8; ++j)
        t[j] = fast_tanh(fmaf(bf2f((ushort)raw[j]), sv[j], hv[j]));
    if (hin) {
        const bf16x8 rv = *(const bf16x8*)(hin + g);
        #pragma unroll
        for (int j = 0; j < 8; ++j) t[j] += bf2f((ushort)rv[j]);
    }
    bf16x8 v;
    #pragma unroll
    for (int j = 0; j < 8; ++j) v[j] = (short)f2bf(t[j]);
    if (hout) *(bf16x8*)(hout + g) = v;
    return v;
}

// ---------------------------------------------------------------------------
// Weight transpose+convert: WT[s][f][k] = bf16(W[s][k][f]).  grid (4,4,ST).
// ---------------------------------------------------------------------------
__global__ __launch_bounds__(256) void k_wtrans(const float* __restrict__ W,
                                                ushort* __restrict__ WT) {
    __shared__ ushort t[64][65];
    const int s = blockIdx.z;
    const int kb = blockIdx.x * 64, fb = blockIdx.y * 64;
    const int tid = threadIdx.x;
    const int c = tid & 63;
    const int r4 = tid >> 6;
    for (int rr = 0; rr < 64; rr += 4) {
        const int r = rr + r4;
        t[r][c] = f2bf(W[(size_t)s * 65536 + (size_t)(kb + r) * 256 + fb + c]);
    }
    __syncthreads();
    for (int rr = 0; rr < 64; rr += 4) {
        const int f = rr + r4;
        WT[(size_t)s * 65536 + (size_t)(fb + f) * 256 + kb + c] = t[c][f];
    }
}

// ---------------------------------------------------------------------------
// att pad+convert: P[s][r][m] = bf16(A[s][r][m]) for r,m<66 else 0.  [80][96]
// ---------------------------------------------------------------------------
__global__ __launch_bounds__(256) void k_aprep(const float* __restrict__ A,
                                               ushort* __restrict__ P,
                                               int S) {
    const int idx = blockIdx.x * 256 + threadIdx.x;
    if (idx >= S * 80 * 96) return;
    const int s = idx / 7680, rm = idx % 7680;
    const int r = rm / 96, m = rm % 96;
    const float v = (r < N_ && m < N_) ? A[(size_t)s * N_ * N_ + r * N_ + m] : 0.f;
    P[idx] = f2bf(v);
}

// ---------------------------------------------------------------------------
// decw pad+transpose: dwT[f][k] = bf16(decw[k][f]) for f<20 else 0.  [32][256]
// ---------------------------------------------------------------------------
__global__ __launch_bounds__(256) void k_dwprep(const float* __restrict__ dw,
                                                ushort* __restrict__ dwT) {
    const int idx = blockIdx.x * 256 + threadIdx.x;
    if (idx >= 32 * 256) return;
    const int f = idx / 256, k = idx % 256;
    const float v = (f < D_) ? dw[(size_t)k * D_ + f] : 0.f;
    dwT[idx] = f2bf(v);
}

// ---------------------------------------------------------------------------
// encw pad+transpose: ewT[f][k] = bf16(encw[k][f]) for k<20 else 0.  [256][32]
// ---------------------------------------------------------------------------
__global__ __launch_bounds__(256) void k_ewprep(const float* __restrict__ ew,
                                                ushort* __restrict__ ewT) {
    const int idx = blockIdx.x * 256 + threadIdx.x;
    if (idx >= 256 * 32) return;
    const int f = idx / 32, k = idx % 32;
    const float v = (k < D_) ? ew[(size_t)k * H_ + f] : 0.f;
    ewT[idx] = f2bf(v);
}

// ---------------------------------------------------------------------------
// DCT along time: xd[b][n][d] = sum_t trans[d][t] * x[b][t][n]
// ---------------------------------------------------------------------------
__global__ __launch_bounds__(256) void k_dct(const float* __restrict__ x,
                                             const float* __restrict__ tm,
                                             float* __restrict__ xd) {
    __shared__ float xs[T_*N_];
    __shared__ float tl[D_*T_];
    const int b = blockIdx.x, tid = threadIdx.x;
    const float* xb = x + (size_t)b * T_ * N_;
    for (int i = tid; i < T_*N_; i += 256) xs[i] = xb[i];
    for (int i = tid; i < D_*T_; i += 256) tl[i] = tm[i];
    __syncthreads();
    for (int p = tid; p < N_*D_; p += 256) {
        const int n = p / D_, d = p % D_;
        float acc = 0.f;
        for (int t = 0; t < T_; ++t)
            acc = fmaf(tl[d*T_ + t], xs[t*N_ + n], acc);
        xd[(size_t)b * N_ * D_ + p] = acc;
    }
}

// ---------------------------------------------------------------------------
// Encoder GC, dual-MFMA: per-batch block. Phase 1 K=32 (20 real), phase 2 attP.
// ---------------------------------------------------------------------------
__global__ __launch_bounds__(256) void k_genc2(const float* __restrict__ xd,
                                               const ushort* __restrict__ ewT,
                                               const ushort* __restrict__ attP,
                                               const float* __restrict__ bias,
                                               ushort* __restrict__ Ybf) {
    __shared__ __align__(16) ushort As[80 * ESTR];       //  6,400 B
    __shared__ __align__(16) ushort XLT[256 * MSTR];     // 53,248 B
    const int b    = blockIdx.x;
    const int tid  = threadIdx.x;
    const int lane = tid & 63;
    const int wc   = tid >> 6;
    const int kq   = lane >> 4;
    const int fr   = lane & 15;

    const int ar1 = tid >> 2;
    const int ak  = (tid & 3) * 8;
    const int ar2 = 64 + (tid >> 2);
    {
        bf16x8 v;
        #pragma unroll
        for (int j = 0; j < 8; ++j) {
            const int k = ak + j;
            v[j] = (k < D_) ? (short)f2bf(xd[((size_t)b * N_ + ar1) * D_ + k]) : (short)0;
        }
        *(bf16x8*)&As[ar1 * ESTR + ak] = v;
    }
    if (tid < 64) {
        bf16x8 v;
        #pragma unroll
        for (int j = 0; j < 8; ++j) {
            const int k = ak + j;
            v[j] = (ar2 < N_ && k < D_) ?
                   (short)f2bf(xd[((size_t)b * N_ + ar2) * D_ + k]) : (short)0;
        }
        *(bf16x8*)&As[ar2 * ESTR + ak] = v;
    }
    __syncthreads();

    f32x4 acc[5][4] = {};
    {
        bf16x8 a[5], bv[4];
        #pragma unroll
        for (int m = 0; m < 5; ++m)
            a[m] = *(const bf16x8*)&As[(m * 16 + fr) * ESTR + kq * 8];
        #pragma unroll
        for (int n = 0; n < 4; ++n)
            bv[n] = *(const bf16x8*)(ewT + (size_t)(wc * 64 + n * 16 + fr) * 32 + kq * 8);
        #pragma unroll
        for (int m = 0; m < 5; ++m)
            #pragma unroll
            for (int n = 0; n < 4; ++n)
                acc[m][n] = __builtin_amdgcn_mfma_f32_16x16x32_bf16(
                                a[m], bv[n], acc[m][n], 0, 0, 0);
    }

    {
        bf16x8 z = {};
        *(bf16x8*)&XLT[(wc * 64 + lane) * MSTR + 80] = z;
        *(bf16x8*)&XLT[(wc * 64 + lane) * MSTR + 88] = z;
    }
    #pragma unroll
    for (int m = 0; m < 5; ++m)
        #pragma unroll
        for (int n = 0; n < 4; ++n)
            #pragma unroll
            for (int j = 0; j < 4; ++j)
                XLT[(wc * 64 + n * 16 + fr) * MSTR + m * 16 + kq * 4 + j] =
                    f2bf(acc[m][n][j]);

    f32x4 acc2[5][4] = {};
    for (int kt = 0; kt < 3; ++kt) {
        const int kb = kt * 32;
        bf16x8 a2[5], b2[4];
        #pragma unroll
        for (int m = 0; m < 5; ++m)
            a2[m] = *(const bf16x8*)(attP + (size_t)(m * 16 + fr) * 96 + kb + kq * 8);
        #pragma unroll
        for (int n = 0; n < 4; ++n)
            b2[n] = *(const bf16x8*)&XLT[(wc * 64 + n * 16 + fr) * MSTR + kb + kq * 8];
        #pragma unroll
        for (int m = 0; m < 5; ++m)
            #pragma unroll
            for (int n = 0; n < 4; ++n)
                acc2[m][n] = __builtin_amdgcn_mfma_f32_16x16x32_bf16(
                                a2[m], b2[n], acc2[m][n], 0, 0, 0);
    }
    float bsv[4];
    #pragma unroll
    for (int n = 0; n < 4; ++n) bsv[n] = bias[wc * 64 + n * 16 + fr];
    #pragma unroll
    for (int m = 0; m < 5; ++m)
        #pragma unroll
        for (int n = 0; n < 4; ++n)
            #pragma unroll
            for (int j = 0; j < 4; ++j) {
                const int row = m * 16 + kq * 4 + j;
                if (row < N_) {
                    const int f = wc * 64 + n * 16 + fr;
                    Ybf[(size_t)b * C_ + row * H_ + f] = f2bf(acc2[m][n][j] + bsv[n]);
                }
            }
}

// ---------------------------------------------------------------------------
// Stage GC, dual-MFMA with fused BN+tanh(+residual update, bf16 h) staging.
// ---------------------------------------------------------------------------
__global__ __launch_bounds__(256) void k_gc(const ushort* __restrict__ Yin,
                                            const float* __restrict__ SC,
                                            const float* __restrict__ SH,
                                            const ushort* __restrict__ hin,
                                            ushort* __restrict__ hout,
                                            const ushort* __restrict__ WT,
                                            const ushort* __restrict__ attP,
                                            const float* __restrict__ bias,
                                            ushort* __restrict__ Ybf) {
    __shared__ __align__(16) ushort smem[256 * MSTR];   // 53,248 B (union)
    ushort* As  = smem;                                 // [80][ASTR] phase 1
    ushort* XLT = smem;                                 // [256][MSTR] phase 2
    const int b    = blockIdx.x;
    const int tid  = threadIdx.x;
    const int lane = tid & 63;
    const int wc   = tid >> 6;
    const int kq   = lane >> 4;
    const int fr   = lane & 15;

    const int ar1 = tid >> 2;
    const int ak  = (tid & 3) * 8;
    const int ar2 = 64 + (tid >> 2);

    for (int kt = 0; kt < 8; ++kt) {
        const int kk = kt * 32 + ak;
        *(bf16x8*)&As[ar1 * ASTR + kk] =
            stage8(Yin, SC, SH, hin, hout, ar1 * H_ + kk,
                   ((size_t)b * N_ + ar1) * H_ + kk);
    }
    if (tid < 64) {
        for (int kt = 0; kt < 8; ++kt) {
            const int kk = kt * 32 + ak;
            bf16x8 v = {};
            if (ar2 < N_)
                v = stage8(Yin, SC, SH, hin, hout, ar2 * H_ + kk,
                           ((size_t)b * N_ + ar2) * H_ + kk);
            *(bf16x8*)&As[ar2 * ASTR + kk] = v;
        }
    }
    __syncthreads();

    // phase 1 k-loop (B from global WT, L2-resident)
    f32x4 acc[5][4] = {};
    for (int kt = 0; kt < 8; ++kt) {
        const int kb = kt * 32;
        bf16x8 a[5], bv[4];
        #pragma unroll
        for (int m = 0; m < 5; ++m)
            a[m] = *(const bf16x8*)&As[(m * 16 + fr) * ASTR + kb + kq * 8];
        #pragma unroll
        for (int n = 0; n < 4; ++n)
            bv[n] = *(const bf16x8*)(WT + (size_t)(wc * 64 + n * 16 + fr) * H_ + kb + kq * 8);
        #pragma unroll
        for (int m = 0; m < 5; ++m)
            #pragma unroll
            for (int n = 0; n < 4; ++n)
                acc[m][n] = __builtin_amdgcn_mfma_f32_16x16x32_bf16(
                                a[m], bv[n], acc[m][n], 0, 0, 0);
    }
    __syncthreads();   // As dead -> reuse as XLT

    {
        bf16x8 z = {};
        *(bf16x8*)&XLT[(wc * 64 + lane) * MSTR + 80] = z;
        *(bf16x8*)&XLT[(wc * 64 + lane) * MSTR + 88] = z;
    }
    #pragma unroll
    for (int m = 0; m < 5; ++m)
        #pragma unroll
        for (int n = 0; n < 4; ++n)
            #pragma unroll
            for (int j = 0; j < 4; ++j)
                XLT[(wc * 64 + n * 16 + fr) * MSTR + m * 16 + kq * 4 + j] =
                    f2bf(acc[m][n][j]);
    // no barrier: each wave reads only its own strip

    f32x4 acc2[5][4] = {};
    for (int kt = 0; kt < 3; ++kt) {
        const int kb = kt * 32;
        bf16x8 a2[5], b2[4];
        #pragma unroll
        for (int m = 0; m < 5; ++m)
            a2[m] = *(const bf16x8*)(attP + (size_t)(m * 16 + fr) * 96 + kb + kq * 8);
        #pragma unroll
        for (int n = 0; n < 4; ++n)
            b2[n] = *(const bf16x8*)&XLT[(wc * 64 + n * 16 + fr) * MSTR + kb + kq * 8];
        #pragma unroll
        for (int m = 0; m < 5; ++m)
            #pragma unroll
            for (int n = 0; n < 4; ++n)
                acc2[m][n] = __builtin_amdgcn_mfma_f32_16x16x32_bf16(
                                a2[m], b2[n], acc2[m][n], 0, 0, 0);
    }
    float bsv[4];
    #pragma unroll
    for (int n = 0; n < 4; ++n) bsv[n] = bias[wc * 64 + n * 16 + fr];
    #pragma unroll
    for (int m = 0; m < 5; ++m)
        #pragma unroll
        for (int n = 0; n < 4; ++n)
            #pragma unroll
            for (int j = 0; j < 4; ++j) {
                const int row = m * 16 + kq * 4 + j;
                if (row < N_) {
                    const int f = wc * 64 + n * 16 + fr;
                    Ybf[(size_t)b * C_ + row * H_ + f] = f2bf(acc2[m][n][j] + bsv[n]);
                }
            }
}

// ---------------------------------------------------------------------------
// BN partial stats over batch group g (bf16 input).  grid (17, NBGS).
// ---------------------------------------------------------------------------
__global__ __launch_bounds__(256) void k_stats(const ushort* __restrict__ v,
                                               float* __restrict__ P1,
                                               float* __restrict__ P2) {
    const int c4 = blockIdx.x * 256 + threadIdx.x;
    if (c4 >= C_ / 4) return;
    const int g = blockIdx.y;
    float4 s1 = make_float4(0.f,0.f,0.f,0.f), s2 = make_float4(0.f,0.f,0.f,0.f);
    const ushort4* vp = (const ushort4*)v;
    for (int i = 0; i < BPGS; ++i) {
        const int b = g * BPGS + i;
        const ushort4 t4 = vp[(size_t)b * (C_ / 4) + c4];
        const float tx = bf2f(t4.x), ty = bf2f(t4.y),
                    tz = bf2f(t4.z), tw = bf2f(t4.w);
        s1.x += tx; s1.y += ty; s1.z += tz; s1.w += tw;
        s2.x = fmaf(tx, tx, s2.x); s2.y = fmaf(ty, ty, s2.y);
        s2.z = fmaf(tz, tz, s2.z); s2.w = fmaf(tw, tw, s2.w);
    }
    ((float4*)(P1 + (size_t)g * C_))[c4] = s1;
    ((float4*)(P2 + (size_t)g * C_))[c4] = s2;
}

// Finalize BN coefficients into SC/SH (reduce NBGS groups).
__global__ __launch_bounds__(256) void k_bnfin(const float* __restrict__ P1,
                                               const float* __restrict__ P2,
                                               const float* __restrict__ gam,
                                               const float* __restrict__ bet,
                                               float* __restrict__ SC,
                                               float* __restrict__ SH) {
    const int c4 = blockIdx.x * 256 + threadIdx.x;
    if (c4 >= C_ / 4) return;
    float4 s1 = make_float4(0.f,0.f,0.f,0.f), s2 = make_float4(0.f,0.f,0.f,0.f);
    for (int g = 0; g < NBGS; ++g) {
        const float4 a = ((const float4*)(P1 + (size_t)g * C_))[c4];
        const float4 b = ((const float4*)(P2 + (size_t)g * C_))[c4];
        s1.x += a.x; s1.y += a.y; s1.z += a.z; s1.w += a.w;
        s2.x += b.x; s2.y += b.y; s2.z += b.z; s2.w += b.w;
    }
    const float inv = 1.f / (float)B_;
    const float4 gm = ((const float4*)gam)[c4];
    const float4 bt = ((const float4*)bet)[c4];
    float4 sc, sh;
    float mu, var;
    mu = s1.x*inv; var = fmaf(-mu, mu, s2.x*inv); sc.x = gm.x*rsqrtf(var+EPS_); sh.x = bt.x - mu*sc.x;
    mu = s1.y*inv; var = fmaf(-mu, mu, s2.y*inv); sc.y = gm.y*rsqrtf(var+EPS_); sh.y = bt.y - mu*sc.y;
    mu = s1.z*inv; var = fmaf(-mu, mu, s2.z*inv); sc.z = gm.z*rsqrtf(var+EPS_); sh.z = bt.z - mu*sc.z;
    mu = s1.w*inv; var = fmaf(-mu, mu, s2.w*inv); sc.w = gm.w*rsqrtf(var+EPS_); sh.w = bt.w - mu*sc.w;
    ((float4*)SC)[c4] = sc;
    ((float4*)SH)[c4] = sh;
}

// ---------------------------------------------------------------------------
// Fully fused decoder with fused final h-update (bf16 h):
// ---------------------------------------------------------------------------
__global__ __launch_bounds__(256) void k_dec2(const ushort* __restrict__ Yin,
                                              const float* __restrict__ SC,
                                              const float* __restrict__ SH,
                                              const ushort* __restrict__ hin,
                                              const ushort* __restrict__ dwT,
                                              const ushort* __restrict__ aPd,
                                              const float* __restrict__ db,
                                              const float* __restrict__ xd,
                                              const float* __restrict__ itm,
                                              const float* __restrict__ x,
                                              float* __restrict__ out) {
    __shared__ __align__(16) ushort As[80 * ASTR];   // 42,240 B
    __shared__ __align__(16) ushort oT[32 * MSTR];   //  6,656 B
    __shared__ float odL[N_ * 21];                   //  5,544 B
    __shared__ float itL[T_ * D_];                   // 10,000 B
    const int b    = blockIdx.x;
    const int tid  = threadIdx.x;
    const int lane = tid & 63;
    const int wc   = tid >> 6;
    const int kq   = lane >> 4;
    const int fr   = lane & 15;

    for (int i = tid; i < T_*D_; i += 256) {
        const int t = i / D_, d = i % D_;
        itL[i] = itm[t * T_ + d];
    }
    const int ar1 = tid >> 2;
    const int ak  = (tid & 3) * 8;
    const int ar2 = 64 + (tid >> 2);
    for (int kt = 0; kt < 8; ++kt) {
        const int kk = kt * 32 + ak;
        *(bf16x8*)&As[ar1 * ASTR + kk] =
            stage8(Yin, SC, SH, hin, nullptr, ar1 * H_ + kk,
                   ((size_t)b * N_ + ar1) * H_ + kk);
    }
    if (tid < 64) {
        for (int kt = 0; kt < 8; ++kt) {
            const int kk = kt * 32 + ak;
            bf16x8 v = {};
            if (ar2 < N_)
                v = stage8(Yin, SC, SH, hin, nullptr, ar2 * H_ + kk,
                           ((size_t)b * N_ + ar2) * H_ + kk);
            *(bf16x8*)&As[ar2 * ASTR + kk] = v;
        }
    }
    if (tid >= 128 && tid < 160) {
        bf16x8 z = {};
        *(bf16x8*)&oT[(tid - 128) * MSTR + 80] = z;
        *(bf16x8*)&oT[(tid - 128) * MSTR + 88] = z;
    }
    __syncthreads();

    if (wc < 2) {
        f32x4 acc[5] = {};
        for (int kt = 0; kt < 8; ++kt) {
            const int kb = kt * 32;
            bf16x8 a[5];
            #pragma unroll
            for (int m = 0; m < 5; ++m)
                a[m] = *(const bf16x8*)&As[(m * 16 + fr) * ASTR + kb + kq * 8];
            const bf16x8 bv = *(const bf16x8*)(dwT + (size_t)(wc * 16 + fr) * H_ + kb + kq * 8);
            #pragma unroll
            for (int m = 0; m < 5; ++m)
                acc[m] = __builtin_amdgcn_mfma_f32_16x16x32_bf16(a[m], bv, acc[m], 0, 0, 0);
        }
        #pragma unroll
        for (int m = 0; m < 5; ++m)
            #pragma unroll
            for (int j = 0; j < 4; ++j)
                oT[(wc * 16 + fr) * MSTR + m * 16 + kq * 4 + j] = f2bf(acc[m][j]);
    }
    __syncthreads();

    if (wc < 2) {
        f32x4 acc2[5] = {};
        for (int kt = 0; kt < 3; ++kt) {
            const int kb = kt * 32;
            bf16x8 a2[5];
            #pragma unroll
            for (int m = 0; m < 5; ++m)
                a2[m] = *(const bf16x8*)(aPd + (size_t)(m * 16 + fr) * 96 + kb + kq * 8);
            const bf16x8 b2 = *(const bf16x8*)&oT[(wc * 16 + fr) * MSTR + kb + kq * 8];
            #pragma unroll
            for (int m = 0; m < 5; ++m)
                acc2[m] = __builtin_amdgcn_mfma_f32_16x16x32_bf16(a2[m], b2, acc2[m], 0, 0, 0);
        }
        const int d = wc * 16 + fr;
        if (d < D_) {
            const float dbv = db[d];
            #pragma unroll
            for (int m = 0; m < 5; ++m)
                #pragma unroll
                for (int j = 0; j < 4; ++j) {
                    const int n = m * 16 + kq * 4 + j;
                    if (n < N_)
                        odL[n * 21 + d] = acc2[m][j] + dbv
                                        + xd[(size_t)b * N_ * D_ + n * D_ + d];
                }
        }
    }
    __syncthreads();

    const float* xb = x + (size_t)b * T_ * N_;
    float* ob = out + (size_t)b * T_ * N_;
    for (int q = tid; q < T_*N_; q += 256) {
        const int t = q / N_, n = q % N_;
        float o;
        if (t < THIS_) {
            o = xb[q];
        } else {
            o = 0.f;
            #pragma unroll 4
            for (int d = 0; d < D_; ++d)
                o = fmaf(itL[t * D_ + d], odL[n * 21 + d], o);
        }
        ob[q] = o;
    }
}

// ---------------------------------------------------------------------------
extern "C" void kernel_launch(void* const* d_in, const int* in_sizes, int n_in,
                              void* d_out, int out_size, void* d_ws, size_t ws_size,
                              hipStream_t stream) {
    const float* x    = (const float*)d_in[0];
    const float* tm   = (const float*)d_in[1];
    const float* itm  = (const float*)d_in[2];
    const float* encw = (const float*)d_in[3];
    const float* enca = (const float*)d_in[4];
    const float* encb = (const float*)d_in[5];
    const float* bn0g = (const float*)d_in[6];
    const float* bn0b = (const float*)d_in[7];
    const float* g1w  = (const float*)d_in[8];
    const float* g1a  = (const float*)d_in[9];
    const float* g1b  = (const float*)d_in[10];
    const float* b1g  = (const float*)d_in[11];
    const float* b1b  = (const float*)d_in[12];
    const float* g2w  = (const float*)d_in[13];
    const float* g2a  = (const float*)d_in[14];
    const float* g2b  = (const float*)d_in[15];
    const float* b2g  = (const float*)d_in[16];
    const float* b2b  = (const float*)d_in[17];
    const float* decw = (const float*)d_in[18];
    const float* deca = (const float*)d_in[19];
    const float* decb = (const float*)d_in[20];
    float* out = (float*)d_out;

    // ws layout (round-1 footprint, proven)
    float* ws = (float*)d_ws;
    float* xd = ws;                         //   675840 floats
    float* hslot = xd + 675840;             //  8650752 floats
    float* slotA = hslot + 8650752;         //  8650752
    float* slotB = slotA + 8650752;         //  8650752
    float* oldP1 = slotB + 8650752;         //   270336 (unused)
    float* oldP2 = oldP1 + 270336;          //   270336 (unused)
    float* SC = oldP2 + 270336;             //    16896
    float* SH = SC + 16896;                 //    16896
    ushort* hbf = (ushort*)hslot;           //  4325376 u16
    ushort* WT1 = (ushort*)slotA;           //   393216 u16
    ushort* WT2 = WT1 + 393216;             //   393216 u16
    ushort* ybf = WT2 + 393216;             //  8650752 u16
    ushort* aP1 = ybf + 8650752;            //    46080 u16
    ushort* aP2 = aP1 + 46080;              //    46080 u16
    ushort* aPd = aP2 + 46080;              //     7680 u16
    ushort* aPe = aPd + 7680;               //     7680 u16
    ushort* dwT = aPe + 7680;               //     8192 u16
    ushort* ewT = dwT + 8192;               //     8192 u16
    float* P1 = slotB;                      //  1081344 f (64 groups)
    float* P2 = P1 + (size_t)NBGS * C_;     //  1081344 f

    const dim3 blk(256);
    const dim3 gS(17, NBGS);

    // preprocessing
    k_wtrans<<<dim3(4,4,ST_), blk, 0, stream>>>(g1w, WT1);
    k_wtrans<<<dim3(4,4,ST_), blk, 0, stream>>>(g2w, WT2);
    k_aprep<<<180, blk, 0, stream>>>(g1a, aP1, ST_);
    k_aprep<<<180, blk, 0, stream>>>(g2a, aP2, ST_);
    k_aprep<<<30, blk, 0, stream>>>(deca, aPd, 1);
    k_aprep<<<30, blk, 0, stream>>>(enca, aPe, 1);
    k_dwprep<<<32, blk, 0, stream>>>(decw, dwT);
    k_ewprep<<<32, blk, 0, stream>>>(encw, ewT);

    k_dct<<<B_, blk, 0, stream>>>(x, tm, xd);

    // encoder (dual-MFMA) -> ybf; bn0 stats+coefs
    k_genc2<<<B_, blk, 0, stream>>>(xd, ewT, aPe, encb, ybf);
    k_stats<<<gS, blk, 0, stream>>>(ybf, P1, P2);
    k_bnfin<<<17, blk, 0, stream>>>(P1, P2, bn0g, bn0b, SC, SH);

    for (int s = 0; s < ST_; ++s) {
        // gc1: A = tanh(bn(y)) (+h for s>0); h updated; ybf = att1*(A@w1)+b1
        k_gc<<<B_, blk, 0, stream>>>(ybf, SC, SH, s ? hbf : nullptr, hbf,
                                     WT1 + s*H_*H_, aP1 + s*7680,
                                     g1b + s*H_, ybf);
        k_stats<<<gS, blk, 0, stream>>>(ybf, P1, P2);
        k_bnfin<<<17, blk, 0, stream>>>(P1, P2, b1g + s*C_, b1b + s*C_, SC, SH);
        // gc2: A = tanh(bn1(y)); ybf = att2*(A@w2)+b2
        k_gc<<<B_, blk, 0, stream>>>(ybf, SC, SH, nullptr, nullptr,
                                     WT2 + s*H_*H_, aP2 + s*7680,
                                     g2b + s*H_, ybf);
        k_stats<<<gS, blk, 0, stream>>>(ybf, P1, P2);
        k_bnfin<<<17, blk, 0, stream>>>(P1, P2, b2g + s*C_, b2b + s*C_, SC, SH);
    }

    // decoder with fused final h-update (h6 = tanh(bn2(y2_5)) + h5)
    k_dec2<<<B_, blk, 0, stream>>>(ybf, SC, SH, hbf, dwT, aPd, decb, xd, itm,
                                   x, out);
}

// Round 19
// 583.972 us; speedup vs baseline: 3.3940x; 1.0212x over previous
//
#include <hip/hip_runtime.h>
#include <math.h>

// Problem dims
#define B_    512
#define T_    125
#define N_    66
#define D_    20
#define H_    256
#define ST_   6
#define THIS_ 25
#define C_    (N_*H_)     // 16896 channels for BN
#define NBGS  64          // batch groups for BN stats
#define BPGS  (B_/NBGS)   // 8
#define EPS_  1e-5f

#define ASTR  264         // As row stride (ushorts)
#define MSTR  104         // XLT/oT row stride (ushorts), 96 used
#define ESTR  40          // genc As row stride (32 used)

typedef __attribute__((ext_vector_type(8))) short bf16x8;
typedef __attribute__((ext_vector_type(4))) float f32x4;

__device__ __forceinline__ ushort f2bf(float f) {
    unsigned u = __float_as_uint(f);
    u += 0x7fffu + ((u >> 16) & 1u);       // round-to-nearest-even
    return (ushort)(u >> 16);
}
__device__ __forceinline__ float bf2f(ushort h) {
    return __uint_as_float((unsigned)h << 16);
}

// tanh(x) = 1 - 2/(e^{2x}+1); v_exp/v_rcp ~1ulp, exact at +-inf.
__device__ __forceinline__ float fast_tanh(float x) {
    float t, r;
    const float z = x * 2.885390081777927f;   // 2*log2(e)
    asm("v_exp_f32 %0, %1" : "=v"(t) : "v"(z));
    const float tp1 = t + 1.f;
    asm("v_rcp_f32 %0, %1" : "=v"(r) : "v"(tp1));
    return 1.f - 2.f * r;
}

// Fused staging element: t = tanh(y*sc+sh) (+ hin bf16); optional hout (bf16).
__device__ __forceinline__ bf16x8 stage8(const ushort* __restrict__ Yin,
                                         const float* __restrict__ SC,
                                         const float* __restrict__ SH,
                                         const ushort* __restrict__ hin,
                                         ushort* __restrict__ hout,
                                         int ch, size_t g) {
    const bf16x8 raw = *(const bf16x8*)(Yin + g);
    float sv[8], hv[8], t[8];
    *(float4*)&sv[0] = *(const float4*)(SC + ch);
    *(float4*)&sv[4] = *(const float4*)(SC + ch + 4);
    *(float4*)&hv[0] = *(const float4*)(SH + ch);
    *(float4*)&hv[4] = *(const float4*)(SH + ch + 4);
    #pragma unroll
    for (int j = 0; j < 8; ++j)
        t[j] = fast_tanh(fmaf(bf2f((ushort)raw[j]), sv[j], hv[j]));
    if (hin) {
        const bf16x8 rv = *(const bf16x8*)(hin + g);
        #pragma unroll
        for (int j = 0; j < 8; ++j) t[j] += bf2f((ushort)rv[j]);
    }
    bf16x8 v;
    #pragma unroll
    for (int j = 0; j < 8; ++j) v[j] = (short)f2bf(t[j]);
    if (hout) *(bf16x8*)(hout + g) = v;
    return v;
}

// ---------------------------------------------------------------------------
// Fused preprocessing + DCT: one kernel, blockIdx-range dispatch.
//   [0,96)    WT1 transpose      (96 = 4x4x6 tiles)
//   [96,192)  WT2 transpose
//   [192,372) aP1 pad            (180 blocks)
//   [372,552) aP2 pad
//   [552,582) aPd pad            (30)
//   [582,612) aPe pad            (30)
//   [612,644) dwT pad-transpose  (32)
//   [644,676) ewT pad-transpose  (32)
//   [676,1188) DCT               (512)
// Per-block math identical to the former separate kernels.
// ---------------------------------------------------------------------------
__device__ void wtrans_blk(const float* __restrict__ W,
                           ushort* __restrict__ WT, int q,
                           ushort (*t)[65]) {
    const int s  = q >> 4;
    const int kb = ((q >> 2) & 3) * 64;
    const int fb = (q & 3) * 64;
    const int tid = threadIdx.x;
    const int c = tid & 63;
    const int r4 = tid >> 6;
    for (int rr = 0; rr < 64; rr += 4) {
        const int r = rr + r4;
        t[r][c] = f2bf(W[(size_t)s * 65536 + (size_t)(kb + r) * 256 + fb + c]);
    }
    __syncthreads();
    for (int rr = 0; rr < 64; rr += 4) {
        const int f = rr + r4;
        WT[(size_t)s * 65536 + (size_t)(fb + f) * 256 + kb + c] = t[c][f];
    }
}

__device__ void aprep_blk(const float* __restrict__ A,
                          ushort* __restrict__ P, int S, int blk) {
    const int idx = blk * 256 + threadIdx.x;
    if (idx >= S * 80 * 96) return;
    const int s = idx / 7680, rm = idx % 7680;
    const int r = rm / 96, m = rm % 96;
    const float v = (r < N_ && m < N_) ? A[(size_t)s * N_ * N_ + r * N_ + m] : 0.f;
    P[idx] = f2bf(v);
}

__global__ __launch_bounds__(256) void k_prep(
        const float* __restrict__ g1w, ushort* __restrict__ WT1,
        const float* __restrict__ g2w, ushort* __restrict__ WT2,
        const float* __restrict__ g1a, ushort* __restrict__ aP1,
        const float* __restrict__ g2a, ushort* __restrict__ aP2,
        const float* __restrict__ deca, ushort* __restrict__ aPd,
        const float* __restrict__ enca, ushort* __restrict__ aPe,
        const float* __restrict__ dw,  ushort* __restrict__ dwT,
        const float* __restrict__ ew,  ushort* __restrict__ ewT,
        const float* __restrict__ x,   const float* __restrict__ tm,
        float* __restrict__ xd) {
    __shared__ ushort t[64][65];          //  8,320 B (wtrans)
    __shared__ float xs[T_*N_];           // 33,000 B (dct)
    __shared__ float tl[D_*T_];           // 10,000 B (dct)
    const int bid = blockIdx.x;
    const int tid = threadIdx.x;

    if (bid < 96) {
        wtrans_blk(g1w, WT1, bid, t);
    } else if (bid < 192) {
        wtrans_blk(g2w, WT2, bid - 96, t);
    } else if (bid < 372) {
        aprep_blk(g1a, aP1, ST_, bid - 192);
    } else if (bid < 552) {
        aprep_blk(g2a, aP2, ST_, bid - 372);
    } else if (bid < 582) {
        aprep_blk(deca, aPd, 1, bid - 552);
    } else if (bid < 612) {
        aprep_blk(enca, aPe, 1, bid - 582);
    } else if (bid < 644) {
        const int idx = (bid - 612) * 256 + tid;
        const int f = idx / 256, k = idx % 256;
        dwT[idx] = f2bf((f < D_) ? dw[(size_t)k * D_ + f] : 0.f);
    } else if (bid < 676) {
        const int idx = (bid - 644) * 256 + tid;
        const int f = idx / 32, k = idx % 32;
        ewT[idx] = f2bf((k < D_) ? ew[(size_t)k * H_ + f] : 0.f);
    } else {
        const int b = bid - 676;
        const float* xb = x + (size_t)b * T_ * N_;
        for (int i = tid; i < T_*N_; i += 256) xs[i] = xb[i];
        for (int i = tid; i < D_*T_; i += 256) tl[i] = tm[i];
        __syncthreads();
        for (int p = tid; p < N_*D_; p += 256) {
            const int n = p / D_, d = p % D_;
            float acc = 0.f;
            for (int tt = 0; tt < T_; ++tt)
                acc = fmaf(tl[d*T_ + tt], xs[tt*N_ + n], acc);
            xd[(size_t)b * N_ * D_ + p] = acc;
        }
    }
}

// ---------------------------------------------------------------------------
// Encoder GC, dual-MFMA: per-batch block. Phase 1 K=32 (20 real), phase 2 attP.
// ---------------------------------------------------------------------------
__global__ __launch_bounds__(256) void k_genc2(const float* __restrict__ xd,
                                               const ushort* __restrict__ ewT,
                                               const ushort* __restrict__ attP,
                                               const float* __restrict__ bias,
                                               ushort* __restrict__ Ybf) {
    __shared__ __align__(16) ushort As[80 * ESTR];       //  6,400 B
    __shared__ __align__(16) ushort XLT[256 * MSTR];     // 53,248 B
    const int b    = blockIdx.x;
    const int tid  = threadIdx.x;
    const int lane = tid & 63;
    const int wc   = tid >> 6;
    const int kq   = lane >> 4;
    const int fr   = lane & 15;

    const int ar1 = tid >> 2;
    const int ak  = (tid & 3) * 8;
    const int ar2 = 64 + (tid >> 2);
    {
        bf16x8 v;
        #pragma unroll
        for (int j = 0; j < 8; ++j) {
            const int k = ak + j;
            v[j] = (k < D_) ? (short)f2bf(xd[((size_t)b * N_ + ar1) * D_ + k]) : (short)0;
        }
        *(bf16x8*)&As[ar1 * ESTR + ak] = v;
    }
    if (tid < 64) {
        bf16x8 v;
        #pragma unroll
        for (int j = 0; j < 8; ++j) {
            const int k = ak + j;
            v[j] = (ar2 < N_ && k < D_) ?
                   (short)f2bf(xd[((size_t)b * N_ + ar2) * D_ + k]) : (short)0;
        }
        *(bf16x8*)&As[ar2 * ESTR + ak] = v;
    }
    __syncthreads();

    f32x4 acc[5][4] = {};
    {
        bf16x8 a[5], bv[4];
        #pragma unroll
        for (int m = 0; m < 5; ++m)
            a[m] = *(const bf16x8*)&As[(m * 16 + fr) * ESTR + kq * 8];
        #pragma unroll
        for (int n = 0; n < 4; ++n)
            bv[n] = *(const bf16x8*)(ewT + (size_t)(wc * 64 + n * 16 + fr) * 32 + kq * 8);
        #pragma unroll
        for (int m = 0; m < 5; ++m)
            #pragma unroll
            for (int n = 0; n < 4; ++n)
                acc[m][n] = __builtin_amdgcn_mfma_f32_16x16x32_bf16(
                                a[m], bv[n], acc[m][n], 0, 0, 0);
    }

    {
        bf16x8 z = {};
        *(bf16x8*)&XLT[(wc * 64 + lane) * MSTR + 80] = z;
        *(bf16x8*)&XLT[(wc * 64 + lane) * MSTR + 88] = z;
    }
    #pragma unroll
    for (int m = 0; m < 5; ++m)
        #pragma unroll
        for (int n = 0; n < 4; ++n)
            #pragma unroll
            for (int j = 0; j < 4; ++j)
                XLT[(wc * 64 + n * 16 + fr) * MSTR + m * 16 + kq * 4 + j] =
                    f2bf(acc[m][n][j]);

    f32x4 acc2[5][4] = {};
    for (int kt = 0; kt < 3; ++kt) {
        const int kb = kt * 32;
        bf16x8 a2[5], b2[4];
        #pragma unroll
        for (int m = 0; m < 5; ++m)
            a2[m] = *(const bf16x8*)(attP + (size_t)(m * 16 + fr) * 96 + kb + kq * 8);
        #pragma unroll
        for (int n = 0; n < 4; ++n)
            b2[n] = *(const bf16x8*)&XLT[(wc * 64 + n * 16 + fr) * MSTR + kb + kq * 8];
        #pragma unroll
        for (int m = 0; m < 5; ++m)
            #pragma unroll
            for (int n = 0; n < 4; ++n)
                acc2[m][n] = __builtin_amdgcn_mfma_f32_16x16x32_bf16(
                                a2[m], b2[n], acc2[m][n], 0, 0, 0);
    }
    float bsv[4];
    #pragma unroll
    for (int n = 0; n < 4; ++n) bsv[n] = bias[wc * 64 + n * 16 + fr];
    #pragma unroll
    for (int m = 0; m < 5; ++m)
        #pragma unroll
        for (int n = 0; n < 4; ++n)
            #pragma unroll
            for (int j = 0; j < 4; ++j) {
                const int row = m * 16 + kq * 4 + j;
                if (row < N_) {
                    const int f = wc * 64 + n * 16 + fr;
                    Ybf[(size_t)b * C_ + row * H_ + f] = f2bf(acc2[m][n][j] + bsv[n]);
                }
            }
}

// ---------------------------------------------------------------------------
// Stage GC, dual-MFMA with fused BN+tanh(+residual update, bf16 h) staging.
// ---------------------------------------------------------------------------
__global__ __launch_bounds__(256) void k_gc(const ushort* __restrict__ Yin,
                                            const float* __restrict__ SC,
                                            const float* __restrict__ SH,
                                            const ushort* __restrict__ hin,
                                            ushort* __restrict__ hout,
                                            const ushort* __restrict__ WT,
                                            const ushort* __restrict__ attP,
                                            const float* __restrict__ bias,
                                            ushort* __restrict__ Ybf) {
    __shared__ __align__(16) ushort smem[256 * MSTR];   // 53,248 B (union)
    ushort* As  = smem;                                 // [80][ASTR] phase 1
    ushort* XLT = smem;                                 // [256][MSTR] phase 2
    const int b    = blockIdx.x;
    const int tid  = threadIdx.x;
    const int lane = tid & 63;
    const int wc   = tid >> 6;
    const int kq   = lane >> 4;
    const int fr   = lane & 15;

    const int ar1 = tid >> 2;
    const int ak  = (tid & 3) * 8;
    const int ar2 = 64 + (tid >> 2);

    for (int kt = 0; kt < 8; ++kt) {
        const int kk = kt * 32 + ak;
        *(bf16x8*)&As[ar1 * ASTR + kk] =
            stage8(Yin, SC, SH, hin, hout, ar1 * H_ + kk,
                   ((size_t)b * N_ + ar1) * H_ + kk);
    }
    if (tid < 64) {
        for (int kt = 0; kt < 8; ++kt) {
            const int kk = kt * 32 + ak;
            bf16x8 v = {};
            if (ar2 < N_)
                v = stage8(Yin, SC, SH, hin, hout, ar2 * H_ + kk,
                           ((size_t)b * N_ + ar2) * H_ + kk);
            *(bf16x8*)&As[ar2 * ASTR + kk] = v;
        }
    }
    __syncthreads();

    // phase 1 k-loop (B from global WT, L2-resident)
    f32x4 acc[5][4] = {};
    for (int kt = 0; kt < 8; ++kt) {
        const int kb = kt * 32;
        bf16x8 a[5], bv[4];
        #pragma unroll
        for (int m = 0; m < 5; ++m)
            a[m] = *(const bf16x8*)&As[(m * 16 + fr) * ASTR + kb + kq * 8];
        #pragma unroll
        for (int n = 0; n < 4; ++n)
            bv[n] = *(const bf16x8*)(WT + (size_t)(wc * 64 + n * 16 + fr) * H_ + kb + kq * 8);
        #pragma unroll
        for (int m = 0; m < 5; ++m)
            #pragma unroll
            for (int n = 0; n < 4; ++n)
                acc[m][n] = __builtin_amdgcn_mfma_f32_16x16x32_bf16(
                                a[m], bv[n], acc[m][n], 0, 0, 0);
    }
    __syncthreads();   // As dead -> reuse as XLT

    {
        bf16x8 z = {};
        *(bf16x8*)&XLT[(wc * 64 + lane) * MSTR + 80] = z;
        *(bf16x8*)&XLT[(wc * 64 + lane) * MSTR + 88] = z;
    }
    #pragma unroll
    for (int m = 0; m < 5; ++m)
        #pragma unroll
        for (int n = 0; n < 4; ++n)
            #pragma unroll
            for (int j = 0; j < 4; ++j)
                XLT[(wc * 64 + n * 16 + fr) * MSTR + m * 16 + kq * 4 + j] =
                    f2bf(acc[m][n][j]);
    // no barrier: each wave reads only its own strip

    f32x4 acc2[5][4] = {};
    for (int kt = 0; kt < 3; ++kt) {
        const int kb = kt * 32;
        bf16x8 a2[5], b2[4];
        #pragma unroll
        for (int m = 0; m < 5; ++m)
            a2[m] = *(const bf16x8*)(attP + (size_t)(m * 16 + fr) * 96 + kb + kq * 8);
        #pragma unroll
        for (int n = 0; n < 4; ++n)
            b2[n] = *(const bf16x8*)&XLT[(wc * 64 + n * 16 + fr) * MSTR + kb + kq * 8];
        #pragma unroll
        for (int m = 0; m < 5; ++m)
            #pragma unroll
            for (int n = 0; n < 4; ++n)
                acc2[m][n] = __builtin_amdgcn_mfma_f32_16x16x32_bf16(
                                a2[m], b2[n], acc2[m][n], 0, 0, 0);
    }
    float bsv[4];
    #pragma unroll
    for (int n = 0; n < 4; ++n) bsv[n] = bias[wc * 64 + n * 16 + fr];
    #pragma unroll
    for (int m = 0; m < 5; ++m)
        #pragma unroll
        for (int n = 0; n < 4; ++n)
            #pragma unroll
            for (int j = 0; j < 4; ++j) {
                const int row = m * 16 + kq * 4 + j;
                if (row < N_) {
                    const int f = wc * 64 + n * 16 + fr;
                    Ybf[(size_t)b * C_ + row * H_ + f] = f2bf(acc2[m][n][j] + bsv[n]);
                }
            }
}

// ---------------------------------------------------------------------------
// BN partial stats over batch group g (bf16 input).  grid (17, NBGS).
// ---------------------------------------------------------------------------
__global__ __launch_bounds__(256) void k_stats(const ushort* __restrict__ v,
                                               float* __restrict__ P1,
                                               float* __restrict__ P2) {
    const int c4 = blockIdx.x * 256 + threadIdx.x;
    if (c4 >= C_ / 4) return;
    const int g = blockIdx.y;
    float4 s1 = make_float4(0.f,0.f,0.f,0.f), s2 = make_float4(0.f,0.f,0.f,0.f);
    const ushort4* vp = (const ushort4*)v;
    for (int i = 0; i < BPGS; ++i) {
        const int b = g * BPGS + i;
        const ushort4 t4 = vp[(size_t)b * (C_ / 4) + c4];
        const float tx = bf2f(t4.x), ty = bf2f(t4.y),
                    tz = bf2f(t4.z), tw = bf2f(t4.w);
        s1.x += tx; s1.y += ty; s1.z += tz; s1.w += tw;
        s2.x = fmaf(tx, tx, s2.x); s2.y = fmaf(ty, ty, s2.y);
        s2.z = fmaf(tz, tz, s2.z); s2.w = fmaf(tw, tw, s2.w);
    }
    ((float4*)(P1 + (size_t)g * C_))[c4] = s1;
    ((float4*)(P2 + (size_t)g * C_))[c4] = s2;
}

// Finalize BN coefficients into SC/SH (reduce NBGS groups).
__global__ __launch_bounds__(256) void k_bnfin(const float* __restrict__ P1,
                                               const float* __restrict__ P2,
                                               const float* __restrict__ gam,
                                               const float* __restrict__ bet,
                                               float* __restrict__ SC,
                                               float* __restrict__ SH) {
    const int c4 = blockIdx.x * 256 + threadIdx.x;
    if (c4 >= C_ / 4) return;
    float4 s1 = make_float4(0.f,0.f,0.f,0.f), s2 = make_float4(0.f,0.f,0.f,0.f);
    for (int g = 0; g < NBGS; ++g) {
        const float4 a = ((const float4*)(P1 + (size_t)g * C_))[c4];
        const float4 b = ((const float4*)(P2 + (size_t)g * C_))[c4];
        s1.x += a.x; s1.y += a.y; s1.z += a.z; s1.w += a.w;
        s2.x += b.x; s2.y += b.y; s2.z += b.z; s2.w += b.w;
    }
    const float inv = 1.f / (float)B_;
    const float4 gm = ((const float4*)gam)[c4];
    const float4 bt = ((const float4*)bet)[c4];
    float4 sc, sh;
    float mu, var;
    mu = s1.x*inv; var = fmaf(-mu, mu, s2.x*inv); sc.x = gm.x*rsqrtf(var+EPS_); sh.x = bt.x - mu*sc.x;
    mu = s1.y*inv; var = fmaf(-mu, mu, s2.y*inv); sc.y = gm.y*rsqrtf(var+EPS_); sh.y = bt.y - mu*sc.y;
    mu = s1.z*inv; var = fmaf(-mu, mu, s2.z*inv); sc.z = gm.z*rsqrtf(var+EPS_); sh.z = bt.z - mu*sc.z;
    mu = s1.w*inv; var = fmaf(-mu, mu, s2.w*inv); sc.w = gm.w*rsqrtf(var+EPS_); sh.w = bt.w - mu*sc.w;
    ((float4*)SC)[c4] = sc;
    ((float4*)SH)[c4] = sh;
}

// ---------------------------------------------------------------------------
// Fully fused decoder with fused final h-update (bf16 h):
// ---------------------------------------------------------------------------
__global__ __launch_bounds__(256) void k_dec2(const ushort* __restrict__ Yin,
                                              const float* __restrict__ SC,
                                              const float* __restrict__ SH,
                                              const ushort* __restrict__ hin,
                                              const ushort* __restrict__ dwT,
                                              const ushort* __restrict__ aPd,
                                              const float* __restrict__ db,
                                              const float* __restrict__ xd,
                                              const float* __restrict__ itm,
                                              const float* __restrict__ x,
                                              float* __restrict__ out) {
    __shared__ __align__(16) ushort As[80 * ASTR];   // 42,240 B
    __shared__ __align__(16) ushort oT[32 * MSTR];   //  6,656 B
    __shared__ float odL[N_ * 21];                   //  5,544 B
    __shared__ float itL[T_ * D_];                   // 10,000 B
    const int b    = blockIdx.x;
    const int tid  = threadIdx.x;
    const int lane = tid & 63;
    const int wc   = tid >> 6;
    const int kq   = lane >> 4;
    const int fr   = lane & 15;

    for (int i = tid; i < T_*D_; i += 256) {
        const int t = i / D_, d = i % D_;
        itL[i] = itm[t * T_ + d];
    }
    const int ar1 = tid >> 2;
    const int ak  = (tid & 3) * 8;
    const int ar2 = 64 + (tid >> 2);
    for (int kt = 0; kt < 8; ++kt) {
        const int kk = kt * 32 + ak;
        *(bf16x8*)&As[ar1 * ASTR + kk] =
            stage8(Yin, SC, SH, hin, nullptr, ar1 * H_ + kk,
                   ((size_t)b * N_ + ar1) * H_ + kk);
    }
    if (tid < 64) {
        for (int kt = 0; kt < 8; ++kt) {
            const int kk = kt * 32 + ak;
            bf16x8 v = {};
            if (ar2 < N_)
                v = stage8(Yin, SC, SH, hin, nullptr, ar2 * H_ + kk,
                           ((size_t)b * N_ + ar2) * H_ + kk);
            *(bf16x8*)&As[ar2 * ASTR + kk] = v;
        }
    }
    if (tid >= 128 && tid < 160) {
        bf16x8 z = {};
        *(bf16x8*)&oT[(tid - 128) * MSTR + 80] = z;
        *(bf16x8*)&oT[(tid - 128) * MSTR + 88] = z;
    }
    __syncthreads();

    if (wc < 2) {
        f32x4 acc[5] = {};
        for (int kt = 0; kt < 8; ++kt) {
            const int kb = kt * 32;
            bf16x8 a[5];
            #pragma unroll
            for (int m = 0; m < 5; ++m)
                a[m] = *(const bf16x8*)&As[(m * 16 + fr) * ASTR + kb + kq * 8];
            const bf16x8 bv = *(const bf16x8*)(dwT + (size_t)(wc * 16 + fr) * H_ + kb + kq * 8);
            #pragma unroll
            for (int m = 0; m < 5; ++m)
                acc[m] = __builtin_amdgcn_mfma_f32_16x16x32_bf16(a[m], bv, acc[m], 0, 0, 0);
        }
        #pragma unroll
        for (int m = 0; m < 5; ++m)
            #pragma unroll
            for (int j = 0; j < 4; ++j)
                oT[(wc * 16 + fr) * MSTR + m * 16 + kq * 4 + j] = f2bf(acc[m][j]);
    }
    __syncthreads();

    if (wc < 2) {
        f32x4 acc2[5] = {};
        for (int kt = 0; kt < 3; ++kt) {
            const int kb = kt * 32;
            bf16x8 a2[5];
            #pragma unroll
            for (int m = 0; m < 5; ++m)
                a2[m] = *(const bf16x8*)(aPd + (size_t)(m * 16 + fr) * 96 + kb + kq * 8);
            const bf16x8 b2 = *(const bf16x8*)&oT[(wc * 16 + fr) * MSTR + kb + kq * 8];
            #pragma unroll
            for (int m = 0; m < 5; ++m)
                acc2[m] = __builtin_amdgcn_mfma_f32_16x16x32_bf16(a2[m], b2, acc2[m], 0, 0, 0);
        }
        const int d = wc * 16 + fr;
        if (d < D_) {
            const float dbv = db[d];
            #pragma unroll
            for (int m = 0; m < 5; ++m)
                #pragma unroll
                for (int j = 0; j < 4; ++j) {
                    const int n = m * 16 + kq * 4 + j;
                    if (n < N_)
                        odL[n * 21 + d] = acc2[m][j] + dbv
                                        + xd[(size_t)b * N_ * D_ + n * D_ + d];
                }
        }
    }
    __syncthreads();

    const float* xb = x + (size_t)b * T_ * N_;
    float* ob = out + (size_t)b * T_ * N_;
    for (int q = tid; q < T_*N_; q += 256) {
        const int t = q / N_, n = q % N_;
        float o;
        if (t < THIS_) {
            o = xb[q];
        } else {
            o = 0.f;
            #pragma unroll 4
            for (int d = 0; d < D_; ++d)
                o = fmaf(itL[t * D_ + d], odL[n * 21 + d], o);
        }
        ob[q] = o;
    }
}

// ---------------------------------------------------------------------------
extern "C" void kernel_launch(void* const* d_in, const int* in_sizes, int n_in,
                              void* d_out, int out_size, void* d_ws, size_t ws_size,
                              hipStream_t stream) {
    const float* x    = (const float*)d_in[0];
    const float* tm   = (const float*)d_in[1];
    const float* itm  = (const float*)d_in[2];
    const float* encw = (const float*)d_in[3];
    const float* enca = (const float*)d_in[4];
    const float* encb = (const float*)d_in[5];
    const float* bn0g = (const float*)d_in[6];
    const float* bn0b = (const float*)d_in[7];
    const float* g1w  = (const float*)d_in[8];
    const float* g1a  = (const float*)d_in[9];
    const float* g1b  = (const float*)d_in[10];
    const float* b1g  = (const float*)d_in[11];
    const float* b1b  = (const float*)d_in[12];
    const float* g2w  = (const float*)d_in[13];
    const float* g2a  = (const float*)d_in[14];
    const float* g2b  = (const float*)d_in[15];
    const float* b2g  = (const float*)d_in[16];
    const float* b2b  = (const float*)d_in[17];
    const float* decw = (const float*)d_in[18];
    const float* deca = (const float*)d_in[19];
    const float* decb = (const float*)d_in[20];
    float* out = (float*)d_out;

    // ws layout (round-1 footprint, proven)
    float* ws = (float*)d_ws;
    float* xd = ws;                         //   675840 floats
    float* hslot = xd + 675840;             //  8650752 floats
    float* slotA = hslot + 8650752;         //  8650752
    float* slotB = slotA + 8650752;         //  8650752
    float* oldP1 = slotB + 8650752;         //   270336 (unused)
    float* oldP2 = oldP1 + 270336;          //   270336 (unused)
    float* SC = oldP2 + 270336;             //    16896
    float* SH = SC + 16896;                 //    16896
    ushort* hbf = (ushort*)hslot;           //  4325376 u16
    ushort* WT1 = (ushort*)slotA;           //   393216 u16
    ushort* WT2 = WT1 + 393216;             //   393216 u16
    ushort* ybf = WT2 + 393216;             //  8650752 u16
    ushort* aP1 = ybf + 8650752;            //    46080 u16
    ushort* aP2 = aP1 + 46080;              //    46080 u16
    ushort* aPd = aP2 + 46080;              //     7680 u16
    ushort* aPe = aPd + 7680;               //     7680 u16
    ushort* dwT = aPe + 7680;               //     8192 u16
    ushort* ewT = dwT + 8192;               //     8192 u16
    float* P1 = slotB;                      //  1081344 f (64 groups)
    float* P2 = P1 + (size_t)NBGS * C_;     //  1081344 f

    const dim3 blk(256);
    const dim3 gS(17, NBGS);

    // fused preprocessing + DCT (one kernel, 1188 blocks)
    k_prep<<<1188, blk, 0, stream>>>(g1w, WT1, g2w, WT2, g1a, aP1, g2a, aP2,
                                     deca, aPd, enca, aPe, decw, dwT,
                                     encw, ewT, x, tm, xd);

    // encoder (dual-MFMA) -> ybf; bn0 stats+coefs
    k_genc2<<<B_, blk, 0, stream>>>(xd, ewT, aPe, encb, ybf);
    k_stats<<<gS, blk, 0, stream>>>(ybf, P1, P2);
    k_bnfin<<<17, blk, 0, stream>>>(P1, P2, bn0g, bn0b, SC, SH);

    for (int s = 0; s < ST_; ++s) {
        // gc1: A = tanh(bn(y)) (+h for s>0); h updated; ybf = att1*(A@w1)+b1
        k_gc<<<B_, blk, 0, stream>>>(ybf, SC, SH, s ? hbf : nullptr, hbf,
                                     WT1 + s*H_*H_, aP1 + s*7680,
                                     g1b + s*H_, ybf);
        k_stats<<<gS, blk, 0, stream>>>(ybf, P1, P2);
        k_bnfin<<<17, blk, 0, stream>>>(P1, P2, b1g + s*C_, b1b + s*C_, SC, SH);
        // gc2: A = tanh(bn1(y)); ybf = att2*(A@w2)+b2
        k_gc<<<B_, blk, 0, stream>>>(ybf, SC, SH, nullptr, nullptr,
                                     WT2 + s*H_*H_, aP2 + s*7680,
                                     g2b + s*H_, ybf);
        k_stats<<<gS, blk, 0, stream>>>(ybf, P1, P2);
        k_bnfin<<<17, blk, 0, stream>>>(P1, P2, b2g + s*C_, b2b + s*C_, SC, SH);
    }

    // decoder with fused final h-update (h6 = tanh(bn2(y2_5)) + h5)
    k_dec2<<<B_, blk, 0, stream>>>(ybf, SC, SH, hbf, dwT, aPd, decb, xd, itm,
                                   x, out);
}